// Round 2
// 669.276 us; speedup vs baseline: 1.0105x; 1.0105x over previous
//
#include <hip/hip_runtime.h>

// CTC batch loss, producer/consumer overlapped.
// One block (16 waves) per batch row. Double-buffered 128-timestep LDS tiles:
//   waves 1..15: gather chunk c+1 (64 label classes + blank per timestep)
//   wave 0     : CTC DP over chunk c, 2 timesteps per shuffle round-trip.
// Renormalization: synchronous exact power-of-2 scaling every 8 steps
// (bit-identical to the verified baseline numerics); the wave-max uses DPP
// row ops (VALU, ~40cy) instead of a ds_swizzle butterfly (~360cy).
// Lane i of wave 0 holds blank-state 2i (bst) and label-state 2i+1 (lst);
// state 128 tracked in b64 (lane 63's copy authoritative).

constexpr int B = 256, T = 512, C = 1024, L = 64;
constexpr int BLK    = 1024;          // 16 waves
constexpr int NW     = BLK / 64;      // 16
constexpr int CHUNK  = 128;           // timesteps per LDS tile
constexpr int NCH    = T / CHUNK;     // 4
constexpr int STRIDE = 66;            // 64 labels + 1 blank + 1 pad (floats)
#define EPSV (1e-7f)
constexpr float LN2F = 0.69314718055994530942f;

__device__ __forceinline__ float flog2(float x) { return __builtin_amdgcn_logf(x); }

// Wave-wide max via DPP row ops; all inputs >= 0. Result broadcast from
// lane 63 (which holds the full max) via readlane -> wave-uniform SGPR.
__device__ __forceinline__ float wave_max_f32(float m) {
#define DPP_MAX(ctrl)                                                        \
    m = fmaxf(m, __int_as_float(__builtin_amdgcn_update_dpp(                 \
            __float_as_int(m), __float_as_int(m), (ctrl), 0xf, 0xf, false)));
    DPP_MAX(0x111);  // row_shr:1
    DPP_MAX(0x112);  // row_shr:2
    DPP_MAX(0x114);  // row_shr:4
    DPP_MAX(0x118);  // row_shr:8   -> lanes 15/31/47/63 hold row maxes
    DPP_MAX(0x142);  // row_bcast15 -> lane31 = rows0-1, lane63 = rows2-3
    DPP_MAX(0x143);  // row_bcast31 -> lane63 = full wave max
#undef DPP_MAX
    return __int_as_float(__builtin_amdgcn_readlane(__float_as_int(m), 63));
}

__global__ __launch_bounds__(BLK, 1)
void ctc_loss_kernel(const int* __restrict__ y_true,
                     const float* __restrict__ y_pred,
                     float* __restrict__ out) {
    __shared__ float e_lds[2][CHUNK * STRIDE];       // 2 x 33792 B

    const int b    = blockIdx.x;
    const int tid  = threadIdx.x;
    const int lane = tid & 63;
    const int wave = tid >> 6;
    const float* p = y_pred + (size_t)b * T * C;

    // --- labels (every wave keeps its own copy; lane i <-> label slot i) ----
    int lab = y_true[b * L + lane];
    int cls = (lab < 0) ? (C - 1) : lab;
    unsigned long long msk = __ballot(lab != -1);
    int ll = __popcll(msk);                          // label length (64 here)
    int clsprev = __shfl_up(cls, 1);
    const bool allow = (lane > 0) && (cls != C - 1) && (cls != clsprev);
    int am1i = __shfl_up((int)allow, 1);
    const bool am1 = (lane > 0) && (am1i != 0);      // allow flag of lane-1

    // --- prologue: gather chunk 0 into tile 0 (all 16 waves, 8 rows each) ---
    {
        const int r0 = wave * (CHUNK / NW);
        float rv[CHUNK / NW];
#pragma unroll
        for (int k = 0; k < CHUNK / NW; ++k)
            rv[k] = p[(size_t)(r0 + k) * C + cls];
        float vb = 0.f;
        if (lane < CHUNK / NW)
            vb = p[(size_t)(r0 + lane) * C + (C - 1)];
#pragma unroll
        for (int k = 0; k < CHUNK / NW; ++k)
            e_lds[0][(r0 + k) * STRIDE + lane] = rv[k] + EPSV;
        if (lane < CHUNK / NW)
            e_lds[0][(r0 + lane) * STRIDE + 64] = vb + EPSV;
    }
    __syncthreads();

    // --- DP state (wave 0) --------------------------------------------------
    float bst = 0.f, lst = 0.f, b64 = 0.f;
    int shift = 0;                                   // cumulative log2 scale

    for (int c = 0; c < NCH; ++c) {
        if (wave != 0) {
            // ===== producer: gather chunk c+1 (waves 1..15) =================
            if (c + 1 < NCH) {
                float* dst = e_lds[(c + 1) & 1];
                const int tb = (c + 1) * CHUNK;
                float rv[9];
#pragma unroll
                for (int k = 0; k < 9; ++k) {
                    int r = (wave - 1) + 15 * k;
                    rv[k] = (r < CHUNK) ? p[(size_t)(tb + r) * C + cls] : 0.f;
                }
                float vb = 0.f;
                int rbk = (wave - 1) + 15 * lane;
                if (lane < 9 && rbk < CHUNK)
                    vb = p[(size_t)(tb + rbk) * C + (C - 1)];
#pragma unroll
                for (int k = 0; k < 9; ++k) {
                    int r = (wave - 1) + 15 * k;
                    if (r < CHUNK) dst[r * STRIDE + lane] = rv[k] + EPSV;
                }
                if (lane < 9 && rbk < CHUNK)
                    dst[rbk * STRIDE + 64] = vb + EPSV;
            }
        } else {
            // ===== consumer: DP over chunk c (wave 0) =======================
            const float* tile = e_lds[c & 1];
            for (int g = 0; g < CHUNK; g += 8) {
                float elr[8], ebr[8], elm1[4];
#pragma unroll
                for (int k = 0; k < 8; ++k) {        // batched LDS reads (MLP)
                    elr[k] = tile[(g + k) * STRIDE + lane];
                    ebr[k] = tile[(g + k) * STRIDE + 64];
                }
#pragma unroll
                for (int j = 0; j < 4; ++j)          // e of lane-1, pair heads
                    elm1[j] = (lane == 0) ? 0.f
                                          : tile[(g + 2 * j) * STRIDE + (lane - 1)];

// two DP timesteps per shuffle round-trip: the three shfls are independent and
// issue together; step2's shifted value sl1 is recomputed locally with the
// exact same operation order as lane-1's l1 (bit-identical to baseline).
#define PAIRSTEP(K) {                                                   \
    float sl  = __shfl_up(lst, 1);                                      \
    float sbv = __shfl_up(bst, 1);                                      \
    float s2l = __shfl_up(lst, 2);                                      \
    if (lane == 0) { sl = 0.f; sbv = 0.f; }                             \
    if (lane < 2)  s2l = 0.f;                                           \
    float b1  = (bst + sl) * ebr[K];                                    \
    float l1  = (lst + bst + (allow ? sl : 0.f)) * elr[K];              \
    float t64 = (b64 + lst) * ebr[K];                                   \
    float sl1 = (lane == 0) ? 0.f                                       \
              : ((sl + sbv + (am1 ? s2l : 0.f)) * elm1[(K) / 2]);       \
    bst = (b1 + sl1) * ebr[(K) + 1];                                    \
    lst = (l1 + b1 + (allow ? sl1 : 0.f)) * elr[(K) + 1];               \
    b64 = (t64 + l1) * ebr[(K) + 1]; }

                if (c == 0 && g == 0) {
                    // t = 0 init
                    bst = (lane == 0) ? ebr[0] : 0.f;
                    lst = (lane == 0 && ll >= 1) ? elr[0] : 0.f;
                    b64 = 0.f;
                    {   // scalar step t = 1
                        float sl = __shfl_up(lst, 1);
                        if (lane == 0) sl = 0.f;
                        float nb  = (bst + sl) * ebr[1];
                        float nl  = (lst + bst + (allow ? sl : 0.f)) * elr[1];
                        float n64 = (b64 + lst) * ebr[1];
                        bst = nb; lst = nl; b64 = n64;
                    }
                    PAIRSTEP(2)
                    PAIRSTEP(4)
                    PAIRSTEP(6)
                } else {
                    PAIRSTEP(0)
                    PAIRSTEP(2)
                    PAIRSTEP(4)
                    PAIRSTEP(6)
                }
#undef PAIRSTEP
                {   // synchronous exact renorm (2^k scaling, wave-uniform)
                    float m = wave_max_f32(fmaxf(fmaxf(bst, lst), b64));
                    unsigned u = __float_as_uint(m);
                    int e = (int)((u >> 23) & 0xFF);
                    int sb = 314 - e;                // target max ~2^60
                    sb = sb > 254 ? 254 : (sb < 1 ? 1 : sb);
                    float sc = __uint_as_float((unsigned)sb << 23);
                    bst *= sc; lst *= sc; b64 *= sc;
                    shift += sb - 127;
                }
            }
        }
        __syncthreads();                             // tile c+1 ready / c free
    }

    // --- epilogue: loss = -ln(alpha[2ll] + alpha[2ll-1]) --------------------
    if (wave == 0) {
        float a_last = (ll == 64) ? __shfl(b64, 63) : __shfl(bst, ll);
        float a_prev = (ll > 0)   ? __shfl(lst, ll - 1) : 0.f;
        if (lane == 0) {
            float s = a_last + a_prev;
            out[b] = -(flog2(s) - (float)shift) * LN2F;
        }
    }
}

extern "C" void kernel_launch(void* const* d_in, const int* in_sizes, int n_in,
                              void* d_out, int out_size, void* d_ws, size_t ws_size,
                              hipStream_t stream) {
    const int*   y_true = (const int*)d_in[0];
    const float* y_pred = (const float*)d_in[1];
    float*       out    = (float*)d_out;
    ctc_loss_kernel<<<B, BLK, 0, stream>>>(y_true, y_pred, out);
}